// Round 1
// baseline (809.153 us; speedup 1.0000x reference)
//
#include <hip/hip_runtime.h>

// ---------------------------------------------------------------------------
// LinkPredictionGNN: 2x GCNConv (self-loops, sym-norm) + pair MLP head.
// Plan:
//   deg/dinv + CSR build (count, scan, scatter)         [int kernels]
//   g1 = dinv * (x @ W1)                                [gemm128, rowscale]
//   h1 = relu(dinv * (gather-sum g1 + g1) + b1)         [agg]
//   g2 = dinv * (h1 @ W2)                               [gemm128]
//   h2 = relu(dinv * (gather-sum g2 + g2) + b2)         [agg]
//   A = h2 @ Wh1[0:128], B = h2 @ Wh1[128:256]          [gemm128 x2]
//   out[p] = relu(A[p0]+B[p1]+bh1) . Wh2 + bh2          [pairs]
// ---------------------------------------------------------------------------

__global__ __launch_bounds__(256) void k_zero_i32(int* __restrict__ p, int n) {
  int i = blockIdx.x * 256 + threadIdx.x;
  if (i < n) p[i] = 0;
}

__global__ __launch_bounds__(256) void k_count(const int* __restrict__ dst,
                                               int* __restrict__ deg, int e) {
  int i = blockIdx.x * 256 + threadIdx.x;
  if (i < e) atomicAdd(&deg[dst[i]], 1);
}

__device__ __forceinline__ int block_excl_scan_256(int v, int* lds) {
  int lane = threadIdx.x & 63;
  int wid = threadIdx.x >> 6;
  int orig = v;
#pragma unroll
  for (int o = 1; o < 64; o <<= 1) {
    int u = __shfl_up(v, o, 64);
    if (lane >= o) v += u;
  }
  if (lane == 63) lds[wid] = v;
  __syncthreads();
  int woff = 0;
#pragma unroll
  for (int w = 0; w < 4; ++w)
    if (w < wid) woff += lds[w];
  return woff + v - orig;
}

__global__ __launch_bounds__(256) void k_block_sum(const int* __restrict__ deg,
                                                   int* __restrict__ bsum, int n) {
  __shared__ int lds[4];
  int i = blockIdx.x * 256 + threadIdx.x;
  int v = (i < n) ? deg[i] : 0;
#pragma unroll
  for (int o = 32; o > 0; o >>= 1) v += __shfl_down(v, o, 64);
  if ((threadIdx.x & 63) == 0) lds[threadIdx.x >> 6] = v;
  __syncthreads();
  if (threadIdx.x == 0) bsum[blockIdx.x] = lds[0] + lds[1] + lds[2] + lds[3];
}

__global__ __launch_bounds__(256) void k_scan_bsums(const int* __restrict__ bsum,
                                                    int* __restrict__ boff, int nb) {
  __shared__ int lds[4];
  int t = threadIdx.x;
  int v = (t < nb) ? bsum[t] : 0;
  int e = block_excl_scan_256(v, lds);
  if (t < nb) boff[t] = e;
}

__global__ __launch_bounds__(256) void k_scan_final(
    const int* __restrict__ deg, const int* __restrict__ boff,
    int* __restrict__ rowptr, int* __restrict__ cursor,
    float* __restrict__ dinv, int n, int e_total) {
  __shared__ int lds[4];
  int i = blockIdx.x * 256 + threadIdx.x;
  int v = (i < n) ? deg[i] : 0;
  int ex = block_excl_scan_256(v, lds);
  if (i < n) {
    int rp = boff[blockIdx.x] + ex;
    rowptr[i] = rp;
    cursor[i] = rp;
    dinv[i] = rsqrtf((float)(v + 1));  // +1 self loop; always > 0
  }
  if (i == 0) rowptr[n] = e_total;
}

__global__ __launch_bounds__(256) void k_scatter(const int* __restrict__ src,
                                                 const int* __restrict__ dst,
                                                 int* __restrict__ cursor,
                                                 int* __restrict__ colarr, int e) {
  int i = blockIdx.x * 256 + threadIdx.x;
  if (i < e) {
    int d = dst[i];
    int pos = atomicAdd(&cursor[d], 1);
    colarr[pos] = src[i];
  }
}

// C[n,128] = rowscale * (X[n,128] @ W[128,128]); rowscale==nullptr -> 1.0
// 64 rows/block, 256 threads, K split in two 64-chunks staged in LDS (48KB).
__global__ __launch_bounds__(256) void k_gemm128(
    const float* __restrict__ X, const float* __restrict__ W,
    const float* __restrict__ rowscale, float* __restrict__ C, int n) {
  __shared__ float4 sW[64 * 32];  // [k_local][c4]  32KB
  __shared__ float4 sX[64 * 16];  // [r][k4_local]  16KB
  int tid = threadIdx.x;
  int row0 = blockIdx.x * 64;
  int tx = tid & 31;  // col4
  int ty = tid >> 5;  // row group (8 rows each)
  float acc[8][4];
#pragma unroll
  for (int r = 0; r < 8; ++r) acc[r][0] = acc[r][1] = acc[r][2] = acc[r][3] = 0.f;
  const float4* W4 = (const float4*)W;
  const float4* X4 = (const float4*)X;
  for (int kc = 0; kc < 2; ++kc) {
    for (int t = tid; t < 64 * 32; t += 256) sW[t] = W4[kc * 64 * 32 + t];
    for (int t = tid; t < 64 * 16; t += 256) {
      int r = t >> 4, c4 = t & 15;
      int gr = row0 + r;
      sX[t] = (gr < n) ? X4[(size_t)gr * 32 + kc * 16 + c4]
                       : make_float4(0.f, 0.f, 0.f, 0.f);
    }
    __syncthreads();
#pragma unroll
    for (int kk = 0; kk < 16; ++kk) {
      float4 w0 = sW[(4 * kk + 0) * 32 + tx];
      float4 w1 = sW[(4 * kk + 1) * 32 + tx];
      float4 w2 = sW[(4 * kk + 2) * 32 + tx];
      float4 w3 = sW[(4 * kk + 3) * 32 + tx];
#pragma unroll
      for (int r = 0; r < 8; ++r) {
        float4 xv = sX[(ty * 8 + r) * 16 + kk];
        acc[r][0] += xv.x * w0.x + xv.y * w1.x + xv.z * w2.x + xv.w * w3.x;
        acc[r][1] += xv.x * w0.y + xv.y * w1.y + xv.z * w2.y + xv.w * w3.y;
        acc[r][2] += xv.x * w0.z + xv.y * w1.z + xv.z * w2.z + xv.w * w3.z;
        acc[r][3] += xv.x * w0.w + xv.y * w1.w + xv.z * w2.w + xv.w * w3.w;
      }
    }
    __syncthreads();
  }
  float4* C4 = (float4*)C;
#pragma unroll
  for (int r = 0; r < 8; ++r) {
    int gr = row0 + ty * 8 + r;
    if (gr < n) {
      float s = rowscale ? rowscale[gr] : 1.f;
      float4 o;
      o.x = acc[r][0] * s; o.y = acc[r][1] * s;
      o.z = acc[r][2] * s; o.w = acc[r][3] * s;
      C4[(size_t)gr * 32 + tx] = o;
    }
  }
}

// out[i,c] = relu(dinv[i] * (g[i,c] + sum_{e in row i} g[col[e],c]) + bias[c])
__global__ __launch_bounds__(128) void k_agg(
    const float* __restrict__ g, const float* __restrict__ dinv,
    const int* __restrict__ rowptr, const int* __restrict__ col,
    const float* __restrict__ bias, float* __restrict__ out, int n) {
  int i = blockIdx.x;
  int c = threadIdx.x;
  __shared__ int scol[128];
  float a0 = g[(size_t)i * 128 + c], a1 = 0.f, a2 = 0.f, a3 = 0.f;
  int beg = rowptr[i], end = rowptr[i + 1];
  for (int base = beg; base < end; base += 128) {
    int m = end - base;
    if (m > 128) m = 128;
    __syncthreads();
    if (c < m) scol[c] = col[base + c];
    __syncthreads();
    int j = 0;
    for (; j + 4 <= m; j += 4) {
      a0 += g[(size_t)scol[j + 0] * 128 + c];
      a1 += g[(size_t)scol[j + 1] * 128 + c];
      a2 += g[(size_t)scol[j + 2] * 128 + c];
      a3 += g[(size_t)scol[j + 3] * 128 + c];
    }
    for (; j < m; ++j) a0 += g[(size_t)scol[j] * 128 + c];
  }
  float acc = (a0 + a1) + (a2 + a3);
  out[(size_t)i * 128 + c] = fmaxf(fmaf(dinv[i], acc, bias[c]), 0.f);
}

// one wave per pair
__global__ __launch_bounds__(256) void k_pairs(
    const float* __restrict__ A, const float* __restrict__ B,
    const int* __restrict__ pairs, const float* __restrict__ bh1,
    const float* __restrict__ wh2, const float* __restrict__ bh2,
    float* __restrict__ out, int P) {
  int p = blockIdx.x * 4 + (threadIdx.x >> 6);
  int lane = threadIdx.x & 63;
  if (p >= P) return;
  int p0 = pairs[2 * p], p1 = pairs[2 * p + 1];
  const float* a = A + (size_t)p0 * 128;
  const float* b = B + (size_t)p1 * 128;
  float v0 = a[lane] + b[lane] + bh1[lane];
  float v1 = a[lane + 64] + b[lane + 64] + bh1[lane + 64];
  v0 = fmaxf(v0, 0.f) * wh2[lane];
  v1 = fmaxf(v1, 0.f) * wh2[lane + 64];
  float s = v0 + v1;
#pragma unroll
  for (int o = 32; o > 0; o >>= 1) s += __shfl_down(s, o, 64);
  if (lane == 0) out[p] = s + bh2[0];
}

extern "C" void kernel_launch(void* const* d_in, const int* in_sizes, int n_in,
                              void* d_out, int out_size, void* d_ws, size_t ws_size,
                              hipStream_t stream) {
  const float* x   = (const float*)d_in[0];
  const int* ei    = (const int*)d_in[1];
  const int* pairs = (const int*)d_in[2];
  const float* W1  = (const float*)d_in[3];
  const float* b1  = (const float*)d_in[4];
  const float* W2  = (const float*)d_in[5];
  const float* b2  = (const float*)d_in[6];
  const float* Wh1 = (const float*)d_in[7];
  const float* bh1 = (const float*)d_in[8];
  const float* Wh2 = (const float*)d_in[9];
  const float* bh2 = (const float*)d_in[10];
  (void)n_in; (void)out_size; (void)ws_size;

  int N = in_sizes[0] / 128;
  int E = in_sizes[1] / 2;
  int P = in_sizes[2] / 2;
  const int* src = ei;
  const int* dst = ei + E;

  char* wsp = (char*)d_ws;
  size_t off = 0;
  auto alloc = [&](size_t bytes) -> void* {
    void* p = wsp + off;
    off += (bytes + 255) & ~(size_t)255;
    return p;
  };
  float* buf0 = (float*)alloc((size_t)N * 128 * 4);
  float* buf1 = (float*)alloc((size_t)N * 128 * 4);
  float* buf2 = (float*)alloc((size_t)N * 128 * 4);
  float* dinv = (float*)alloc((size_t)N * 4);
  int* deg    = (int*)alloc((size_t)N * 4);
  int* rowptr = (int*)alloc((size_t)(N + 1) * 4);
  int* cursor = (int*)alloc((size_t)N * 4);
  int* colarr = (int*)alloc((size_t)E * 4);
  int NB = (N + 255) / 256;
  int* bsum = (int*)alloc((size_t)NB * 4);
  int* boff = (int*)alloc((size_t)NB * 4);

  // CSR + degree
  k_zero_i32<<<(N + 255) / 256, 256, 0, stream>>>(deg, N);
  k_count<<<(E + 255) / 256, 256, 0, stream>>>(dst, deg, E);
  k_block_sum<<<NB, 256, 0, stream>>>(deg, bsum, N);
  k_scan_bsums<<<1, 256, 0, stream>>>(bsum, boff, NB);
  k_scan_final<<<NB, 256, 0, stream>>>(deg, boff, rowptr, cursor, dinv, N, E);
  k_scatter<<<(E + 255) / 256, 256, 0, stream>>>(src, dst, cursor, colarr, E);

  int GB = (N + 63) / 64;
  // conv1
  k_gemm128<<<GB, 256, 0, stream>>>(x, W1, dinv, buf0, N);
  k_agg<<<N, 128, 0, stream>>>(buf0, dinv, rowptr, colarr, b1, buf1, N);
  // conv2
  k_gemm128<<<GB, 256, 0, stream>>>(buf1, W2, dinv, buf0, N);
  k_agg<<<N, 128, 0, stream>>>(buf0, dinv, rowptr, colarr, b2, buf2, N);
  // head: A = h2 @ Wh1_top, B = h2 @ Wh1_bot
  k_gemm128<<<GB, 256, 0, stream>>>(buf2, Wh1, nullptr, buf0, N);
  k_gemm128<<<GB, 256, 0, stream>>>(buf2, Wh1 + 128 * 128, nullptr, buf1, N);
  k_pairs<<<(P + 3) / 4, 256, 0, stream>>>(buf0, buf1, pairs, bh1, Wh2, bh2,
                                           (float*)d_out, P);
}

// Round 2
// 759.726 us; speedup vs baseline: 1.0651x; 1.0651x over previous
//
#include <hip/hip_runtime.h>

// ---------------------------------------------------------------------------
// LinkPredictionGNN: 2x GCNConv (self-loops, sym-norm) + pair MLP head.
//   deg/dinv + CSR build (count, scan, scatter)         [int kernels]
//   g1 = dinv * (x @ W1)                                [gemm128, rowscale]
//   h1 = relu(dinv * (gather-sum g1 + g1) + b1)         [agg]
//   g2 = dinv * (h1 @ W2)                               [gemm128]
//   h2 = relu(dinv * (gather-sum g2 + g2) + b2)         [agg]
//   A = h2 @ Wh1[0:128], B = h2 @ Wh1[128:256]          [gemm128 x2]
//   out[p] = relu(A[p0]+B[p1]+bh1) . Wh2 + bh2          [pairs]
//
// R1: count/scatter were write-amplification bound (WRITE_SIZE 101MB for a
// 6.4MB payload; random 4B writes -> per-line writeback across 8 XCD L2s).
// Now dst-range partitioned: block b handles node range b%8 (one XCD per
// range via round-robin dispatch) over edge chunk b/8, so scatter writes and
// deg/cursor atomics stay L2-resident until lines fill.
// ---------------------------------------------------------------------------

#define NRANGE 8
#define NCHUNK 128

__global__ __launch_bounds__(256) void k_zero_i32(int* __restrict__ p, int n) {
  int i = blockIdx.x * 256 + threadIdx.x;
  if (i < n) p[i] = 0;
}

// partitioned degree count: block handles dst in [lo,hi) over one edge chunk
__global__ __launch_bounds__(256) void k_count_part(const int* __restrict__ dst,
                                                    int* __restrict__ deg,
                                                    int e, int rsz, int ch) {
  int range = blockIdx.x & (NRANGE - 1);
  int chunk = blockIdx.x / NRANGE;
  int lo = range * rsz, hi = lo + rsz;
  int beg = chunk * ch + threadIdx.x;
  int end = min(e, (chunk + 1) * ch);
  for (int i = beg; i < end; i += 256) {
    int d = dst[i];
    if (d >= lo && d < hi) atomicAdd(&deg[d], 1);
  }
}

__device__ __forceinline__ int block_excl_scan_256(int v, int* lds) {
  int lane = threadIdx.x & 63;
  int wid = threadIdx.x >> 6;
  int orig = v;
#pragma unroll
  for (int o = 1; o < 64; o <<= 1) {
    int u = __shfl_up(v, o, 64);
    if (lane >= o) v += u;
  }
  if (lane == 63) lds[wid] = v;
  __syncthreads();
  int woff = 0;
#pragma unroll
  for (int w = 0; w < 4; ++w)
    if (w < wid) woff += lds[w];
  return woff + v - orig;
}

__global__ __launch_bounds__(256) void k_block_sum(const int* __restrict__ deg,
                                                   int* __restrict__ bsum, int n) {
  __shared__ int lds[4];
  int i = blockIdx.x * 256 + threadIdx.x;
  int v = (i < n) ? deg[i] : 0;
#pragma unroll
  for (int o = 32; o > 0; o >>= 1) v += __shfl_down(v, o, 64);
  if ((threadIdx.x & 63) == 0) lds[threadIdx.x >> 6] = v;
  __syncthreads();
  if (threadIdx.x == 0) bsum[blockIdx.x] = lds[0] + lds[1] + lds[2] + lds[3];
}

__global__ __launch_bounds__(256) void k_scan_bsums(const int* __restrict__ bsum,
                                                    int* __restrict__ boff, int nb) {
  __shared__ int lds[4];
  int t = threadIdx.x;
  int v = (t < nb) ? bsum[t] : 0;
  int e = block_excl_scan_256(v, lds);
  if (t < nb) boff[t] = e;
}

__global__ __launch_bounds__(256) void k_scan_final(
    const int* __restrict__ deg, const int* __restrict__ boff,
    int* __restrict__ rowptr, int* __restrict__ cursor,
    float* __restrict__ dinv, int n, int e_total) {
  __shared__ int lds[4];
  int i = blockIdx.x * 256 + threadIdx.x;
  int v = (i < n) ? deg[i] : 0;
  int ex = block_excl_scan_256(v, lds);
  if (i < n) {
    int rp = boff[blockIdx.x] + ex;
    rowptr[i] = rp;
    cursor[i] = rp;
    dinv[i] = rsqrtf((float)(v + 1));  // +1 self loop; always > 0
  }
  if (i == 0) rowptr[n] = e_total;
}

// partitioned scatter: writes into colarr confined to this range's rowptr
// region (~E/NRANGE*4B contiguous) -> stays in the XCD L2 until lines fill.
__global__ __launch_bounds__(256) void k_scatter_part(const int* __restrict__ src,
                                                      const int* __restrict__ dst,
                                                      int* __restrict__ cursor,
                                                      int* __restrict__ colarr,
                                                      int e, int rsz, int ch) {
  int range = blockIdx.x & (NRANGE - 1);
  int chunk = blockIdx.x / NRANGE;
  int lo = range * rsz, hi = lo + rsz;
  int beg = chunk * ch + threadIdx.x;
  int end = min(e, (chunk + 1) * ch);
  for (int i = beg; i < end; i += 256) {
    int d = dst[i];
    if (d >= lo && d < hi) {
      int pos = atomicAdd(&cursor[d], 1);
      colarr[pos] = src[i];
    }
  }
}

// C[n,128] = rowscale * (X[n,128] @ W[128,128]); rowscale==nullptr -> 1.0
// 64 rows/block, 256 threads, K split in two 64-chunks staged in LDS (48KB).
__global__ __launch_bounds__(256) void k_gemm128(
    const float* __restrict__ X, const float* __restrict__ W,
    const float* __restrict__ rowscale, float* __restrict__ C, int n) {
  __shared__ float4 sW[64 * 32];  // [k_local][c4]  32KB
  __shared__ float4 sX[64 * 16];  // [r][k4_local]  16KB
  int tid = threadIdx.x;
  int row0 = blockIdx.x * 64;
  int tx = tid & 31;  // col4
  int ty = tid >> 5;  // row group (8 rows each)
  float acc[8][4];
#pragma unroll
  for (int r = 0; r < 8; ++r) acc[r][0] = acc[r][1] = acc[r][2] = acc[r][3] = 0.f;
  const float4* W4 = (const float4*)W;
  const float4* X4 = (const float4*)X;
  for (int kc = 0; kc < 2; ++kc) {
    for (int t = tid; t < 64 * 32; t += 256) sW[t] = W4[kc * 64 * 32 + t];
    for (int t = tid; t < 64 * 16; t += 256) {
      int r = t >> 4, c4 = t & 15;
      int gr = row0 + r;
      sX[t] = (gr < n) ? X4[(size_t)gr * 32 + kc * 16 + c4]
                       : make_float4(0.f, 0.f, 0.f, 0.f);
    }
    __syncthreads();
#pragma unroll
    for (int kk = 0; kk < 16; ++kk) {
      float4 w0 = sW[(4 * kk + 0) * 32 + tx];
      float4 w1 = sW[(4 * kk + 1) * 32 + tx];
      float4 w2 = sW[(4 * kk + 2) * 32 + tx];
      float4 w3 = sW[(4 * kk + 3) * 32 + tx];
#pragma unroll
      for (int r = 0; r < 8; ++r) {
        float4 xv = sX[(ty * 8 + r) * 16 + kk];
        acc[r][0] += xv.x * w0.x + xv.y * w1.x + xv.z * w2.x + xv.w * w3.x;
        acc[r][1] += xv.x * w0.y + xv.y * w1.y + xv.z * w2.y + xv.w * w3.y;
        acc[r][2] += xv.x * w0.z + xv.y * w1.z + xv.z * w2.z + xv.w * w3.z;
        acc[r][3] += xv.x * w0.w + xv.y * w1.w + xv.z * w2.w + xv.w * w3.w;
      }
    }
    __syncthreads();
  }
  float4* C4 = (float4*)C;
#pragma unroll
  for (int r = 0; r < 8; ++r) {
    int gr = row0 + ty * 8 + r;
    if (gr < n) {
      float s = rowscale ? rowscale[gr] : 1.f;
      float4 o;
      o.x = acc[r][0] * s; o.y = acc[r][1] * s;
      o.z = acc[r][2] * s; o.w = acc[r][3] * s;
      C4[(size_t)gr * 32 + tx] = o;
    }
  }
}

// out[i,c] = relu(dinv[i] * (g[i,c] + sum_{e in row i} g[col[e],c]) + bias[c])
__global__ __launch_bounds__(128) void k_agg(
    const float* __restrict__ g, const float* __restrict__ dinv,
    const int* __restrict__ rowptr, const int* __restrict__ col,
    const float* __restrict__ bias, float* __restrict__ out, int n) {
  int i = blockIdx.x;
  int c = threadIdx.x;
  __shared__ int scol[128];
  float a0 = g[(size_t)i * 128 + c], a1 = 0.f, a2 = 0.f, a3 = 0.f;
  int beg = rowptr[i], end = rowptr[i + 1];
  for (int base = beg; base < end; base += 128) {
    int m = end - base;
    if (m > 128) m = 128;
    __syncthreads();
    if (c < m) scol[c] = col[base + c];
    __syncthreads();
    int j = 0;
    for (; j + 4 <= m; j += 4) {
      a0 += g[(size_t)scol[j + 0] * 128 + c];
      a1 += g[(size_t)scol[j + 1] * 128 + c];
      a2 += g[(size_t)scol[j + 2] * 128 + c];
      a3 += g[(size_t)scol[j + 3] * 128 + c];
    }
    for (; j < m; ++j) a0 += g[(size_t)scol[j] * 128 + c];
  }
  float acc = (a0 + a1) + (a2 + a3);
  out[(size_t)i * 128 + c] = fmaxf(fmaf(dinv[i], acc, bias[c]), 0.f);
}

// one wave per pair
__global__ __launch_bounds__(256) void k_pairs(
    const float* __restrict__ A, const float* __restrict__ B,
    const int* __restrict__ pairs, const float* __restrict__ bh1,
    const float* __restrict__ wh2, const float* __restrict__ bh2,
    float* __restrict__ out, int P) {
  int p = blockIdx.x * 4 + (threadIdx.x >> 6);
  int lane = threadIdx.x & 63;
  if (p >= P) return;
  int p0 = pairs[2 * p], p1 = pairs[2 * p + 1];
  const float* a = A + (size_t)p0 * 128;
  const float* b = B + (size_t)p1 * 128;
  float v0 = a[lane] + b[lane] + bh1[lane];
  float v1 = a[lane + 64] + b[lane + 64] + bh1[lane + 64];
  v0 = fmaxf(v0, 0.f) * wh2[lane];
  v1 = fmaxf(v1, 0.f) * wh2[lane + 64];
  float s = v0 + v1;
#pragma unroll
  for (int o = 32; o > 0; o >>= 1) s += __shfl_down(s, o, 64);
  if (lane == 0) out[p] = s + bh2[0];
}

extern "C" void kernel_launch(void* const* d_in, const int* in_sizes, int n_in,
                              void* d_out, int out_size, void* d_ws, size_t ws_size,
                              hipStream_t stream) {
  const float* x   = (const float*)d_in[0];
  const int* ei    = (const int*)d_in[1];
  const int* pairs = (const int*)d_in[2];
  const float* W1  = (const float*)d_in[3];
  const float* b1  = (const float*)d_in[4];
  const float* W2  = (const float*)d_in[5];
  const float* b2  = (const float*)d_in[6];
  const float* Wh1 = (const float*)d_in[7];
  const float* bh1 = (const float*)d_in[8];
  const float* Wh2 = (const float*)d_in[9];
  const float* bh2 = (const float*)d_in[10];
  (void)n_in; (void)out_size; (void)ws_size;

  int N = in_sizes[0] / 128;
  int E = in_sizes[1] / 2;
  int P = in_sizes[2] / 2;
  const int* src = ei;
  const int* dst = ei + E;

  char* wsp = (char*)d_ws;
  size_t off = 0;
  auto alloc = [&](size_t bytes) -> void* {
    void* p = wsp + off;
    off += (bytes + 255) & ~(size_t)255;
    return p;
  };
  float* buf0 = (float*)alloc((size_t)N * 128 * 4);
  float* buf1 = (float*)alloc((size_t)N * 128 * 4);
  float* buf2 = (float*)alloc((size_t)N * 128 * 4);
  float* dinv = (float*)alloc((size_t)N * 4);
  int* deg    = (int*)alloc((size_t)N * 4);
  int* rowptr = (int*)alloc((size_t)(N + 1) * 4);
  int* cursor = (int*)alloc((size_t)N * 4);
  int* colarr = (int*)alloc((size_t)E * 4);
  int NB = (N + 255) / 256;
  int* bsum = (int*)alloc((size_t)NB * 4);
  int* boff = (int*)alloc((size_t)NB * 4);

  int rsz = (N + NRANGE - 1) / NRANGE;      // nodes per range
  int ch  = (E + NCHUNK - 1) / NCHUNK;      // edges per chunk
  int part_grid = NRANGE * NCHUNK;

  // CSR + degree
  k_zero_i32<<<(N + 255) / 256, 256, 0, stream>>>(deg, N);
  k_count_part<<<part_grid, 256, 0, stream>>>(dst, deg, E, rsz, ch);
  k_block_sum<<<NB, 256, 0, stream>>>(deg, bsum, N);
  k_scan_bsums<<<1, 256, 0, stream>>>(bsum, boff, NB);
  k_scan_final<<<NB, 256, 0, stream>>>(deg, boff, rowptr, cursor, dinv, N, E);
  k_scatter_part<<<part_grid, 256, 0, stream>>>(src, dst, cursor, colarr, E, rsz, ch);

  int GB = (N + 63) / 64;
  // conv1
  k_gemm128<<<GB, 256, 0, stream>>>(x, W1, dinv, buf0, N);
  k_agg<<<N, 128, 0, stream>>>(buf0, dinv, rowptr, colarr, b1, buf1, N);
  // conv2
  k_gemm128<<<GB, 256, 0, stream>>>(buf1, W2, dinv, buf0, N);
  k_agg<<<N, 128, 0, stream>>>(buf0, dinv, rowptr, colarr, b2, buf2, N);
  // head: A = h2 @ Wh1_top, B = h2 @ Wh1_bot
  k_gemm128<<<GB, 256, 0, stream>>>(buf2, Wh1, nullptr, buf0, N);
  k_gemm128<<<GB, 256, 0, stream>>>(buf2, Wh1 + 128 * 128, nullptr, buf1, N);
  k_pairs<<<(P + 3) / 4, 256, 0, stream>>>(buf0, buf1, pairs, bh1, Wh2, bh2,
                                           (float*)d_out, P);
}

// Round 3
// 677.390 us; speedup vs baseline: 1.1945x; 1.1215x over previous
//
#include <hip/hip_runtime.h>
#include <hip/hip_fp16.h>

// ---------------------------------------------------------------------------
// LinkPredictionGNN: 2x GCNConv (self-loops, sym-norm) + pair MLP head.
//   deg/dinv + CSR build (count, scan, scatter)         [int kernels]
//   g1 = fp16( dinv * (x @ W1) )                        [gemm128 -> fp16]
//   h1 = relu(dinv * (gather-sum g1 + g1) + b1)         [agg_h, fp16 gather]
//   g2 = fp16( dinv * (h1 @ W2) )                       [gemm128]
//   h2 = relu(dinv * (gather-sum g2 + g2) + b2)         [agg_h]
//   A = fp16(h2 @ Wh1[0:128]), B = fp16(h2 @ Wh1[128:]) [gemm128 x2]
//   out[p] = relu(A[p0]+B[p1]+bh1) . Wh2 + bh2          [pairs_h]
//
// R1: scatter write-amplification fixed via dst-range/XCD partitioning.
// R2: agg was L2-miss-BW bound (FETCH 359MB vs 25.6MB fp32 table). Message
// table + head A/B tables now fp16 (12.8MB): halves gather bytes and raises
// L2 hit rate. fp16 (2^-12 rel err), NOT bf16 — keeps absmax ~1e-4 << 1.5e-3.
// ---------------------------------------------------------------------------

#define NRANGE 8
#define NCHUNK 128

struct __align__(8) half4 { __half2 a, b; };

__global__ __launch_bounds__(256) void k_zero_i32(int* __restrict__ p, int n) {
  int i = blockIdx.x * 256 + threadIdx.x;
  if (i < n) p[i] = 0;
}

// partitioned degree count: block handles dst in [lo,hi) over one edge chunk
__global__ __launch_bounds__(256) void k_count_part(const int* __restrict__ dst,
                                                    int* __restrict__ deg,
                                                    int e, int rsz, int ch) {
  int range = blockIdx.x & (NRANGE - 1);
  int chunk = blockIdx.x / NRANGE;
  int lo = range * rsz, hi = lo + rsz;
  int beg = chunk * ch + threadIdx.x;
  int end = min(e, (chunk + 1) * ch);
  for (int i = beg; i < end; i += 256) {
    int d = dst[i];
    if (d >= lo && d < hi) atomicAdd(&deg[d], 1);
  }
}

__device__ __forceinline__ int block_excl_scan_256(int v, int* lds) {
  int lane = threadIdx.x & 63;
  int wid = threadIdx.x >> 6;
  int orig = v;
#pragma unroll
  for (int o = 1; o < 64; o <<= 1) {
    int u = __shfl_up(v, o, 64);
    if (lane >= o) v += u;
  }
  if (lane == 63) lds[wid] = v;
  __syncthreads();
  int woff = 0;
#pragma unroll
  for (int w = 0; w < 4; ++w)
    if (w < wid) woff += lds[w];
  return woff + v - orig;
}

__global__ __launch_bounds__(256) void k_block_sum(const int* __restrict__ deg,
                                                   int* __restrict__ bsum, int n) {
  __shared__ int lds[4];
  int i = blockIdx.x * 256 + threadIdx.x;
  int v = (i < n) ? deg[i] : 0;
#pragma unroll
  for (int o = 32; o > 0; o >>= 1) v += __shfl_down(v, o, 64);
  if ((threadIdx.x & 63) == 0) lds[threadIdx.x >> 6] = v;
  __syncthreads();
  if (threadIdx.x == 0) bsum[blockIdx.x] = lds[0] + lds[1] + lds[2] + lds[3];
}

__global__ __launch_bounds__(256) void k_scan_bsums(const int* __restrict__ bsum,
                                                    int* __restrict__ boff, int nb) {
  __shared__ int lds[4];
  int t = threadIdx.x;
  int v = (t < nb) ? bsum[t] : 0;
  int e = block_excl_scan_256(v, lds);
  if (t < nb) boff[t] = e;
}

__global__ __launch_bounds__(256) void k_scan_final(
    const int* __restrict__ deg, const int* __restrict__ boff,
    int* __restrict__ rowptr, int* __restrict__ cursor,
    float* __restrict__ dinv, int n, int e_total) {
  __shared__ int lds[4];
  int i = blockIdx.x * 256 + threadIdx.x;
  int v = (i < n) ? deg[i] : 0;
  int ex = block_excl_scan_256(v, lds);
  if (i < n) {
    int rp = boff[blockIdx.x] + ex;
    rowptr[i] = rp;
    cursor[i] = rp;
    dinv[i] = rsqrtf((float)(v + 1));  // +1 self loop; always > 0
  }
  if (i == 0) rowptr[n] = e_total;
}

// partitioned scatter: writes confined to this range's contiguous CSR region
__global__ __launch_bounds__(256) void k_scatter_part(const int* __restrict__ src,
                                                      const int* __restrict__ dst,
                                                      int* __restrict__ cursor,
                                                      int* __restrict__ colarr,
                                                      int e, int rsz, int ch) {
  int range = blockIdx.x & (NRANGE - 1);
  int chunk = blockIdx.x / NRANGE;
  int lo = range * rsz, hi = lo + rsz;
  int beg = chunk * ch + threadIdx.x;
  int end = min(e, (chunk + 1) * ch);
  for (int i = beg; i < end; i += 256) {
    int d = dst[i];
    if (d >= lo && d < hi) {
      int pos = atomicAdd(&cursor[d], 1);
      colarr[pos] = src[i];
    }
  }
}

// C16[n,128] = fp16( rowscale * (X[n,128] @ W[128,128]) ); rowscale null -> 1
// 64 rows/block, 256 threads, K in two 64-chunks staged in LDS (48KB).
__global__ __launch_bounds__(256) void k_gemm128(
    const float* __restrict__ X, const float* __restrict__ W,
    const float* __restrict__ rowscale, __half* __restrict__ C16, int n) {
  __shared__ float4 sW[64 * 32];  // [k_local][c4]  32KB
  __shared__ float4 sX[64 * 16];  // [r][k4_local]  16KB
  int tid = threadIdx.x;
  int row0 = blockIdx.x * 64;
  int tx = tid & 31;  // col4
  int ty = tid >> 5;  // row group (8 rows each)
  float acc[8][4];
#pragma unroll
  for (int r = 0; r < 8; ++r) acc[r][0] = acc[r][1] = acc[r][2] = acc[r][3] = 0.f;
  const float4* W4 = (const float4*)W;
  const float4* X4 = (const float4*)X;
  for (int kc = 0; kc < 2; ++kc) {
    for (int t = tid; t < 64 * 32; t += 256) sW[t] = W4[kc * 64 * 32 + t];
    for (int t = tid; t < 64 * 16; t += 256) {
      int r = t >> 4, c4 = t & 15;
      int gr = row0 + r;
      sX[t] = (gr < n) ? X4[(size_t)gr * 32 + kc * 16 + c4]
                       : make_float4(0.f, 0.f, 0.f, 0.f);
    }
    __syncthreads();
#pragma unroll
    for (int kk = 0; kk < 16; ++kk) {
      float4 w0 = sW[(4 * kk + 0) * 32 + tx];
      float4 w1 = sW[(4 * kk + 1) * 32 + tx];
      float4 w2 = sW[(4 * kk + 2) * 32 + tx];
      float4 w3 = sW[(4 * kk + 3) * 32 + tx];
#pragma unroll
      for (int r = 0; r < 8; ++r) {
        float4 xv = sX[(ty * 8 + r) * 16 + kk];
        acc[r][0] += xv.x * w0.x + xv.y * w1.x + xv.z * w2.x + xv.w * w3.x;
        acc[r][1] += xv.x * w0.y + xv.y * w1.y + xv.z * w2.y + xv.w * w3.y;
        acc[r][2] += xv.x * w0.z + xv.y * w1.z + xv.z * w2.z + xv.w * w3.z;
        acc[r][3] += xv.x * w0.w + xv.y * w1.w + xv.z * w2.w + xv.w * w3.w;
      }
    }
    __syncthreads();
  }
  half4* G = (half4*)C16;  // 32 half4 per row
#pragma unroll
  for (int r = 0; r < 8; ++r) {
    int gr = row0 + ty * 8 + r;
    if (gr < n) {
      float s = rowscale ? rowscale[gr] : 1.f;
      half4 o;
      o.a = __floats2half2_rn(acc[r][0] * s, acc[r][1] * s);
      o.b = __floats2half2_rn(acc[r][2] * s, acc[r][3] * s);
      G[(size_t)gr * 32 + tx] = o;
    }
  }
}

// out[i,:] = relu(dinv[i] * (g[i,:] + sum_{e in row i} g[col[e],:]) + bias)
// fp16 message table; 64 lanes per row, one half2 (2 cols) per lane.
__global__ __launch_bounds__(256) void k_agg_h(
    const __half2* __restrict__ g2, const float* __restrict__ dinv,
    const int* __restrict__ rowptr, const int* __restrict__ col,
    const float* __restrict__ bias, float* __restrict__ out, int n) {
  int i = blockIdx.x * 4 + (threadIdx.x >> 6);
  int c = threadIdx.x & 63;  // half2 column index
  if (i >= n) return;
  float2 a0 = __half22float2(g2[(size_t)i * 64 + c]);  // self loop
  float2 a1 = make_float2(0.f, 0.f);
  float2 a2 = make_float2(0.f, 0.f);
  float2 a3 = make_float2(0.f, 0.f);
  int beg = rowptr[i], end = rowptr[i + 1];
  int j = beg;
  for (; j + 4 <= end; j += 4) {
    int s0 = col[j], s1 = col[j + 1], s2 = col[j + 2], s3 = col[j + 3];
    float2 v0 = __half22float2(g2[(size_t)s0 * 64 + c]);
    float2 v1 = __half22float2(g2[(size_t)s1 * 64 + c]);
    float2 v2 = __half22float2(g2[(size_t)s2 * 64 + c]);
    float2 v3 = __half22float2(g2[(size_t)s3 * 64 + c]);
    a0.x += v0.x; a0.y += v0.y;
    a1.x += v1.x; a1.y += v1.y;
    a2.x += v2.x; a2.y += v2.y;
    a3.x += v3.x; a3.y += v3.y;
  }
  for (; j < end; ++j) {
    float2 v = __half22float2(g2[(size_t)col[j] * 64 + c]);
    a0.x += v.x; a0.y += v.y;
  }
  float di = dinv[i];
  float2 bi = ((const float2*)bias)[c];
  float2 o;
  o.x = fmaxf(fmaf(di, (a0.x + a1.x) + (a2.x + a3.x), bi.x), 0.f);
  o.y = fmaxf(fmaf(di, (a0.y + a1.y) + (a2.y + a3.y), bi.y), 0.f);
  ((float2*)out)[(size_t)i * 64 + c] = o;
}

// one wave per pair, fp16 A/B tables, half2 per lane
__global__ __launch_bounds__(256) void k_pairs_h(
    const __half2* __restrict__ A, const __half2* __restrict__ B,
    const int* __restrict__ pairs, const float* __restrict__ bh1,
    const float* __restrict__ wh2, const float* __restrict__ bh2,
    float* __restrict__ out, int P) {
  int p = blockIdx.x * 4 + (threadIdx.x >> 6);
  int c = threadIdx.x & 63;
  if (p >= P) return;
  int p0 = pairs[2 * p], p1 = pairs[2 * p + 1];
  float2 av = __half22float2(A[(size_t)p0 * 64 + c]);
  float2 bv = __half22float2(B[(size_t)p1 * 64 + c]);
  float2 bi = ((const float2*)bh1)[c];
  float2 wv = ((const float2*)wh2)[c];
  float v0 = fmaxf(av.x + bv.x + bi.x, 0.f) * wv.x;
  float v1 = fmaxf(av.y + bv.y + bi.y, 0.f) * wv.y;
  float s = v0 + v1;
#pragma unroll
  for (int o = 32; o > 0; o >>= 1) s += __shfl_down(s, o, 64);
  if (c == 0) out[p] = s + bh2[0];
}

extern "C" void kernel_launch(void* const* d_in, const int* in_sizes, int n_in,
                              void* d_out, int out_size, void* d_ws, size_t ws_size,
                              hipStream_t stream) {
  const float* x   = (const float*)d_in[0];
  const int* ei    = (const int*)d_in[1];
  const int* pairs = (const int*)d_in[2];
  const float* W1  = (const float*)d_in[3];
  const float* b1  = (const float*)d_in[4];
  const float* W2  = (const float*)d_in[5];
  const float* b2  = (const float*)d_in[6];
  const float* Wh1 = (const float*)d_in[7];
  const float* bh1 = (const float*)d_in[8];
  const float* Wh2 = (const float*)d_in[9];
  const float* bh2 = (const float*)d_in[10];
  (void)n_in; (void)out_size; (void)ws_size;

  int N = in_sizes[0] / 128;
  int E = in_sizes[1] / 2;
  int P = in_sizes[2] / 2;
  const int* src = ei;
  const int* dst = ei + E;

  char* wsp = (char*)d_ws;
  size_t off = 0;
  auto alloc = [&](size_t bytes) -> void* {
    void* p = wsp + off;
    off += (bytes + 255) & ~(size_t)255;
    return p;
  };
  __half* g16 = (__half*)alloc((size_t)N * 128 * 2);  // messages; reused as A16
  float* h1   = (float*)alloc((size_t)N * 128 * 4);   // reused as B16 (fp16)
  float* h2   = (float*)alloc((size_t)N * 128 * 4);
  float* dinv = (float*)alloc((size_t)N * 4);
  int* deg    = (int*)alloc((size_t)N * 4);
  int* rowptr = (int*)alloc((size_t)(N + 1) * 4);
  int* cursor = (int*)alloc((size_t)N * 4);
  int* colarr = (int*)alloc((size_t)E * 4);
  int NB = (N + 255) / 256;
  int* bsum = (int*)alloc((size_t)NB * 4);
  int* boff = (int*)alloc((size_t)NB * 4);
  __half* A16 = g16;            // g2 dead by the time head runs
  __half* B16 = (__half*)h1;    // h1 dead after conv2 gemm

  int rsz = (N + NRANGE - 1) / NRANGE;  // nodes per range
  int ch  = (E + NCHUNK - 1) / NCHUNK;  // edges per chunk
  int part_grid = NRANGE * NCHUNK;

  // CSR + degree
  k_zero_i32<<<(N + 255) / 256, 256, 0, stream>>>(deg, N);
  k_count_part<<<part_grid, 256, 0, stream>>>(dst, deg, E, rsz, ch);
  k_block_sum<<<NB, 256, 0, stream>>>(deg, bsum, N);
  k_scan_bsums<<<1, 256, 0, stream>>>(bsum, boff, NB);
  k_scan_final<<<NB, 256, 0, stream>>>(deg, boff, rowptr, cursor, dinv, N, E);
  k_scatter_part<<<part_grid, 256, 0, stream>>>(src, dst, cursor, colarr, E, rsz, ch);

  int GB = (N + 63) / 64;
  int AB = (N + 3) / 4;
  // conv1
  k_gemm128<<<GB, 256, 0, stream>>>(x, W1, dinv, g16, N);
  k_agg_h<<<AB, 256, 0, stream>>>((const __half2*)g16, dinv, rowptr, colarr, b1, h1, N);
  // conv2
  k_gemm128<<<GB, 256, 0, stream>>>(h1, W2, dinv, g16, N);
  k_agg_h<<<AB, 256, 0, stream>>>((const __half2*)g16, dinv, rowptr, colarr, b2, h2, N);
  // head: A = h2 @ Wh1_top, B = h2 @ Wh1_bot
  k_gemm128<<<GB, 256, 0, stream>>>(h2, Wh1, nullptr, A16, N);
  k_gemm128<<<GB, 256, 0, stream>>>(h2, Wh1 + 128 * 128, nullptr, B16, N);
  k_pairs_h<<<(P + 3) / 4, 256, 0, stream>>>((const __half2*)A16, (const __half2*)B16,
                                             pairs, bh1, Wh2, bh2, (float*)d_out, P);
}

// Round 4
// 471.168 us; speedup vs baseline: 1.7173x; 1.4377x over previous
//
#include <hip/hip_runtime.h>
#include <hip/hip_fp16.h>

// ---------------------------------------------------------------------------
// LinkPredictionGNN: 2x GCNConv (self-loops, sym-norm) + pair MLP head.
//   deg/dinv + CSR build (count, scan, scatter)         [int kernels]
//   prep: W1/W2/Wh1_top/Wh1_bot -> bf16 hi/lo B-frags   [k_prep_w, 256KB]
//   g1 = fp16( dinv * (x @ W1) )                        [k_gemm_mfma]
//   h1 = relu(dinv * (gather-sum g1 + g1) + b1)         [agg_h, fp16 gather]
//   g2 = fp16( dinv * (h1 @ W2) )                       [k_gemm_mfma]
//   h2 = relu(dinv * (gather-sum g2 + g2) + b2)         [agg_h]
//   A = fp16(h2 @ Wh1_top), B = fp16(h2 @ Wh1_bot)      [k_gemm_mfma x2]
//   out[p] = relu(A[p0]+B[p1]+bh1) . Wh2 + bh2          [pairs_h]
//
// R1: scatter write-amplification fixed via dst-range/XCD partitioning.
// R2: fp16 message/A/B tables halve gather bytes (absmax 4.9e-4 < 1.5e-3).
// R3: fp32-vector GEMM was latency/occupancy-bound (87us, VALUBusy 21%,
// occ 8.4%). Replaced with double-bf16-split MFMA GEMM (Ah.Bh+Al.Bh+Ah.Bl,
// rel err ~2^-16 << fp16 storage err): no LDS, no barriers, W-frags
// L2-resident; pure X-streaming ~10us/gemm roofline.
// ---------------------------------------------------------------------------

#define NRANGE 8
#define NCHUNK 128

typedef __attribute__((ext_vector_type(8))) short bf16x8;
typedef __attribute__((ext_vector_type(4))) float f32x4;

struct __align__(8) half4 { __half2 a, b; };

__global__ __launch_bounds__(256) void k_zero_i32(int* __restrict__ p, int n) {
  int i = blockIdx.x * 256 + threadIdx.x;
  if (i < n) p[i] = 0;
}

// partitioned degree count: block handles dst in [lo,hi) over one edge chunk
__global__ __launch_bounds__(256) void k_count_part(const int* __restrict__ dst,
                                                    int* __restrict__ deg,
                                                    int e, int rsz, int ch) {
  int range = blockIdx.x & (NRANGE - 1);
  int chunk = blockIdx.x / NRANGE;
  int lo = range * rsz, hi = lo + rsz;
  int beg = chunk * ch + threadIdx.x;
  int end = min(e, (chunk + 1) * ch);
  for (int i = beg; i < end; i += 256) {
    int d = dst[i];
    if (d >= lo && d < hi) atomicAdd(&deg[d], 1);
  }
}

__device__ __forceinline__ int block_excl_scan_256(int v, int* lds) {
  int lane = threadIdx.x & 63;
  int wid = threadIdx.x >> 6;
  int orig = v;
#pragma unroll
  for (int o = 1; o < 64; o <<= 1) {
    int u = __shfl_up(v, o, 64);
    if (lane >= o) v += u;
  }
  if (lane == 63) lds[wid] = v;
  __syncthreads();
  int woff = 0;
#pragma unroll
  for (int w = 0; w < 4; ++w)
    if (w < wid) woff += lds[w];
  return woff + v - orig;
}

__global__ __launch_bounds__(256) void k_block_sum(const int* __restrict__ deg,
                                                   int* __restrict__ bsum, int n) {
  __shared__ int lds[4];
  int i = blockIdx.x * 256 + threadIdx.x;
  int v = (i < n) ? deg[i] : 0;
#pragma unroll
  for (int o = 32; o > 0; o >>= 1) v += __shfl_down(v, o, 64);
  if ((threadIdx.x & 63) == 0) lds[threadIdx.x >> 6] = v;
  __syncthreads();
  if (threadIdx.x == 0) bsum[blockIdx.x] = lds[0] + lds[1] + lds[2] + lds[3];
}

__global__ __launch_bounds__(256) void k_scan_bsums(const int* __restrict__ bsum,
                                                    int* __restrict__ boff, int nb) {
  __shared__ int lds[4];
  int t = threadIdx.x;
  int v = (t < nb) ? bsum[t] : 0;
  int e = block_excl_scan_256(v, lds);
  if (t < nb) boff[t] = e;
}

__global__ __launch_bounds__(256) void k_scan_final(
    const int* __restrict__ deg, const int* __restrict__ boff,
    int* __restrict__ rowptr, int* __restrict__ cursor,
    float* __restrict__ dinv, int n, int e_total) {
  __shared__ int lds[4];
  int i = blockIdx.x * 256 + threadIdx.x;
  int v = (i < n) ? deg[i] : 0;
  int ex = block_excl_scan_256(v, lds);
  if (i < n) {
    int rp = boff[blockIdx.x] + ex;
    rowptr[i] = rp;
    cursor[i] = rp;
    dinv[i] = rsqrtf((float)(v + 1));  // +1 self loop; always > 0
  }
  if (i == 0) rowptr[n] = e_total;
}

// partitioned scatter: writes confined to this range's contiguous CSR region
__global__ __launch_bounds__(256) void k_scatter_part(const int* __restrict__ src,
                                                      const int* __restrict__ dst,
                                                      int* __restrict__ cursor,
                                                      int* __restrict__ colarr,
                                                      int e, int rsz, int ch) {
  int range = blockIdx.x & (NRANGE - 1);
  int chunk = blockIdx.x / NRANGE;
  int lo = range * rsz, hi = lo + rsz;
  int beg = chunk * ch + threadIdx.x;
  int end = min(e, (chunk + 1) * ch);
  for (int i = beg; i < end; i += 256) {
    int d = dst[i];
    if (d >= lo && d < hi) {
      int pos = atomicAdd(&cursor[d], 1);
      colarr[pos] = src[i];
    }
  }
}

// --- MFMA GEMM machinery ----------------------------------------------------
// Exact split: x = hi(bf16, trunc) + lo(bf16, trunc) + O(2^-17 |x|).
__device__ __forceinline__ void split8(const float* v, bf16x8& hi, bf16x8& lo) {
#pragma unroll
  for (int j = 0; j < 8; ++j) {
    unsigned u = __float_as_uint(v[j]);
    hi[j] = (short)(u >> 16);
    float lf = v[j] - __uint_as_float(u & 0xffff0000u);
    lo[j] = (short)(__float_as_uint(lf) >> 16);
  }
}

// Precompute B-operand bf16 hi/lo fragments for the 4 weight matrices.
// Slot g = ((w*8 + t)*4 + s)*64 + lane ; lane holds B[k=s*32+quad*8+j][n=16t+(lane&15)]
__global__ __launch_bounds__(256) void k_prep_w(
    const float* __restrict__ W1, const float* __restrict__ W2,
    const float* __restrict__ Wh1, short* __restrict__ fragH,
    short* __restrict__ fragL) {
  int g = blockIdx.x * 256 + threadIdx.x;
  if (g >= 4 * 2048) return;
  int w = g >> 11;
  int rem = g & 2047;
  int lane = rem & 63;
  int ts = rem >> 6;          // t*4 + s
  int t = ts >> 2, s = ts & 3;
  int n = (t << 4) + (lane & 15);
  int k0 = s * 32 + (lane >> 4) * 8;
  const float* W = (w == 0) ? W1 : (w == 1) ? W2 : (w == 2) ? Wh1 : (Wh1 + 128 * 128);
  short h[8], l[8];
#pragma unroll
  for (int j = 0; j < 8; ++j) {
    float x = W[(k0 + j) * 128 + n];
    unsigned u = __float_as_uint(x);
    h[j] = (short)(u >> 16);
    float lf = x - __uint_as_float(u & 0xffff0000u);
    l[j] = (short)(__float_as_uint(lf) >> 16);
  }
  ((int4*)fragH)[g] = *(int4*)h;
  ((int4*)fragL)[g] = *(int4*)l;
}

// C16[n,128] = fp16( rowscale * (X[n,128] @ W) ) via 16x16x32 bf16 MFMA.
// One wave = 16 rows x 128 cols. No LDS, no barriers.
__global__ __launch_bounds__(256) void k_gemm_mfma(
    const float* __restrict__ X, const short* __restrict__ fragH,
    const short* __restrict__ fragL, const float* __restrict__ rowscale,
    __half* __restrict__ C16, int n) {
  int wid = threadIdx.x >> 6, lane = threadIdx.x & 63;
  int r0 = (blockIdx.x * 4 + wid) * 16;
  if (r0 >= n) return;
  int m = lane & 15, quad = lane >> 4;
  const float* xrow = X + (size_t)(r0 + m) * 128;
  f32x4 acc[8];
#pragma unroll
  for (int t = 0; t < 8; ++t) acc[t] = (f32x4)(0.f);
  const int4* FH = (const int4*)fragH;
  const int4* FL = (const int4*)fragL;
#pragma unroll
  for (int s = 0; s < 4; ++s) {
    int k0 = s * 32 + quad * 8;
    float xv[8];
    *(float4*)&xv[0] = *(const float4*)(xrow + k0);
    *(float4*)&xv[4] = *(const float4*)(xrow + k0 + 4);
    bf16x8 ah, al;
    split8(xv, ah, al);
#pragma unroll
    for (int t = 0; t < 8; ++t) {
      int idx = (t * 4 + s) * 64 + lane;
      bf16x8 bh = *(const bf16x8*)&FH[idx];
      bf16x8 bl = *(const bf16x8*)&FL[idx];
      acc[t] = __builtin_amdgcn_mfma_f32_16x16x32_bf16(ah, bh, acc[t], 0, 0, 0);
      acc[t] = __builtin_amdgcn_mfma_f32_16x16x32_bf16(al, bh, acc[t], 0, 0, 0);
      acc[t] = __builtin_amdgcn_mfma_f32_16x16x32_bf16(ah, bl, acc[t], 0, 0, 0);
    }
  }
  // C/D layout: col = lane&15, row = quad*4 + reg   [m89-verified mapping]
  float sc[4];
#pragma unroll
  for (int r = 0; r < 4; ++r)
    sc[r] = rowscale ? rowscale[r0 + quad * 4 + r] : 1.f;
#pragma unroll
  for (int t = 0; t < 8; ++t) {
#pragma unroll
    for (int r = 0; r < 4; ++r) {
      int row = r0 + quad * 4 + r;
      C16[(size_t)row * 128 + t * 16 + m] = __float2half(acc[t][r] * sc[r]);
    }
  }
}

// out[i,:] = relu(dinv[i] * (g[i,:] + sum_{e in row i} g[col[e],:]) + bias)
// fp16 message table; 64 lanes per row, one half2 (2 cols) per lane.
__global__ __launch_bounds__(256) void k_agg_h(
    const __half2* __restrict__ g2, const float* __restrict__ dinv,
    const int* __restrict__ rowptr, const int* __restrict__ col,
    const float* __restrict__ bias, float* __restrict__ out, int n) {
  int i = blockIdx.x * 4 + (threadIdx.x >> 6);
  int c = threadIdx.x & 63;  // half2 column index
  if (i >= n) return;
  float2 a0 = __half22float2(g2[(size_t)i * 64 + c]);  // self loop
  float2 a1 = make_float2(0.f, 0.f);
  float2 a2 = make_float2(0.f, 0.f);
  float2 a3 = make_float2(0.f, 0.f);
  int beg = rowptr[i], end = rowptr[i + 1];
  int j = beg;
  for (; j + 4 <= end; j += 4) {
    int s0 = col[j], s1 = col[j + 1], s2 = col[j + 2], s3 = col[j + 3];
    float2 v0 = __half22float2(g2[(size_t)s0 * 64 + c]);
    float2 v1 = __half22float2(g2[(size_t)s1 * 64 + c]);
    float2 v2 = __half22float2(g2[(size_t)s2 * 64 + c]);
    float2 v3 = __half22float2(g2[(size_t)s3 * 64 + c]);
    a0.x += v0.x; a0.y += v0.y;
    a1.x += v1.x; a1.y += v1.y;
    a2.x += v2.x; a2.y += v2.y;
    a3.x += v3.x; a3.y += v3.y;
  }
  for (; j < end; ++j) {
    float2 v = __half22float2(g2[(size_t)col[j] * 64 + c]);
    a0.x += v.x; a0.y += v.y;
  }
  float di = dinv[i];
  float2 bi = ((const float2*)bias)[c];
  float2 o;
  o.x = fmaxf(fmaf(di, (a0.x + a1.x) + (a2.x + a3.x), bi.x), 0.f);
  o.y = fmaxf(fmaf(di, (a0.y + a1.y) + (a2.y + a3.y), bi.y), 0.f);
  ((float2*)out)[(size_t)i * 64 + c] = o;
}

// one wave per pair, fp16 A/B tables, half2 per lane
__global__ __launch_bounds__(256) void k_pairs_h(
    const __half2* __restrict__ A, const __half2* __restrict__ B,
    const int* __restrict__ pairs, const float* __restrict__ bh1,
    const float* __restrict__ wh2, const float* __restrict__ bh2,
    float* __restrict__ out, int P) {
  int p = blockIdx.x * 4 + (threadIdx.x >> 6);
  int c = threadIdx.x & 63;
  if (p >= P) return;
  int p0 = pairs[2 * p], p1 = pairs[2 * p + 1];
  float2 av = __half22float2(A[(size_t)p0 * 64 + c]);
  float2 bv = __half22float2(B[(size_t)p1 * 64 + c]);
  float2 bi = ((const float2*)bh1)[c];
  float2 wv = ((const float2*)wh2)[c];
  float v0 = fmaxf(av.x + bv.x + bi.x, 0.f) * wv.x;
  float v1 = fmaxf(av.y + bv.y + bi.y, 0.f) * wv.y;
  float s = v0 + v1;
#pragma unroll
  for (int o = 32; o > 0; o >>= 1) s += __shfl_down(s, o, 64);
  if (c == 0) out[p] = s + bh2[0];
}

extern "C" void kernel_launch(void* const* d_in, const int* in_sizes, int n_in,
                              void* d_out, int out_size, void* d_ws, size_t ws_size,
                              hipStream_t stream) {
  const float* x   = (const float*)d_in[0];
  const int* ei    = (const int*)d_in[1];
  const int* pairs = (const int*)d_in[2];
  const float* W1  = (const float*)d_in[3];
  const float* b1  = (const float*)d_in[4];
  const float* W2  = (const float*)d_in[5];
  const float* b2  = (const float*)d_in[6];
  const float* Wh1 = (const float*)d_in[7];
  const float* bh1 = (const float*)d_in[8];
  const float* Wh2 = (const float*)d_in[9];
  const float* bh2 = (const float*)d_in[10];
  (void)n_in; (void)out_size; (void)ws_size;

  int N = in_sizes[0] / 128;
  int E = in_sizes[1] / 2;
  int P = in_sizes[2] / 2;
  const int* src = ei;
  const int* dst = ei + E;

  char* wsp = (char*)d_ws;
  size_t off = 0;
  auto alloc = [&](size_t bytes) -> void* {
    void* p = wsp + off;
    off += (bytes + 255) & ~(size_t)255;
    return p;
  };
  __half* g16 = (__half*)alloc((size_t)N * 128 * 2);  // messages; reused as A16
  float* h1   = (float*)alloc((size_t)N * 128 * 4);   // reused as B16 (fp16)
  float* h2   = (float*)alloc((size_t)N * 128 * 4);
  float* dinv = (float*)alloc((size_t)N * 4);
  int* deg    = (int*)alloc((size_t)N * 4);
  int* rowptr = (int*)alloc((size_t)(N + 1) * 4);
  int* cursor = (int*)alloc((size_t)N * 4);
  int* colarr = (int*)alloc((size_t)E * 4);
  short* fragH = (short*)alloc(4 * 2048 * 8 * 2);  // 128KB
  short* fragL = (short*)alloc(4 * 2048 * 8 * 2);  // 128KB
  int NB = (N + 255) / 256;
  int* bsum = (int*)alloc((size_t)NB * 4);
  int* boff = (int*)alloc((size_t)NB * 4);
  __half* A16 = g16;            // g16 dead by the time head runs
  __half* B16 = (__half*)h1;    // h1 dead after conv2 gemm
  // per-W frag bases (2048 slots * 8 shorts each)
  short* fH_W1 = fragH + 0 * 16384;  short* fL_W1 = fragL + 0 * 16384;
  short* fH_W2 = fragH + 1 * 16384;  short* fL_W2 = fragL + 1 * 16384;
  short* fH_Wa = fragH + 2 * 16384;  short* fL_Wa = fragL + 2 * 16384;
  short* fH_Wb = fragH + 3 * 16384;  short* fL_Wb = fragL + 3 * 16384;

  int rsz = (N + NRANGE - 1) / NRANGE;  // nodes per range
  int ch  = (E + NCHUNK - 1) / NCHUNK;  // edges per chunk
  int part_grid = NRANGE * NCHUNK;

  // weight fragment prep (independent of CSR)
  k_prep_w<<<32, 256, 0, stream>>>(W1, W2, Wh1, fragH, fragL);

  // CSR + degree
  k_zero_i32<<<(N + 255) / 256, 256, 0, stream>>>(deg, N);
  k_count_part<<<part_grid, 256, 0, stream>>>(dst, deg, E, rsz, ch);
  k_block_sum<<<NB, 256, 0, stream>>>(deg, bsum, N);
  k_scan_bsums<<<1, 256, 0, stream>>>(bsum, boff, NB);
  k_scan_final<<<NB, 256, 0, stream>>>(deg, boff, rowptr, cursor, dinv, N, E);
  k_scatter_part<<<part_grid, 256, 0, stream>>>(src, dst, cursor, colarr, E, rsz, ch);

  int GB = (N / 16 + 3) / 4;  // waves of 16 rows, 4 per block
  int AB = (N + 3) / 4;
  // conv1
  k_gemm_mfma<<<GB, 256, 0, stream>>>(x, fH_W1, fL_W1, dinv, g16, N);
  k_agg_h<<<AB, 256, 0, stream>>>((const __half2*)g16, dinv, rowptr, colarr, b1, h1, N);
  // conv2
  k_gemm_mfma<<<GB, 256, 0, stream>>>(h1, fH_W2, fL_W2, dinv, g16, N);
  k_agg_h<<<AB, 256, 0, stream>>>((const __half2*)g16, dinv, rowptr, colarr, b2, h2, N);
  // head: A = h2 @ Wh1_top, B = h2 @ Wh1_bot
  k_gemm_mfma<<<GB, 256, 0, stream>>>(h2, fH_Wa, fL_Wa, nullptr, A16, N);
  k_gemm_mfma<<<GB, 256, 0, stream>>>(h2, fH_Wb, fL_Wb, nullptr, B16, N);
  k_pairs_h<<<(P + 3) / 4, 256, 0, stream>>>((const __half2*)A16, (const __half2*)B16,
                                             pairs, bh1, Wh2, bh2, (float*)d_out, P);
}